// Round 10
// baseline (42.406 us; speedup 1.0000x reference)
//
#include <hip/hip_runtime.h>
#include <math.h>

namespace {
constexpr int KB    = 16;        // spline bins
constexpr int OUTP  = 3*KB + 1;  // 49
constexpr int CDIM  = 64;
constexpr int HDIM  = 256;
constexpr int NCOL  = 1024;
constexpr int NROW  = 4096;
constexpr float BOUNDF = 5.0f;
constexpr float MBW_ = 0.001f;
constexpr float MBH_ = 0.001f;
constexpr float MD_  = 0.001f;
constexpr int PSTR  = 51;   // 17 cumw | 17 cumh | 17 deriv
constexpr int MROWS = 16;   // rows per MLP block (one 16-row M-tile)
constexpr int HSTR  = 260;  // padded LDS stride (uints): 16B-aligned, 2-way banks
constexpr int N3    = 64;   // layer-3 cols padded 49 -> 64
}

typedef __attribute__((ext_vector_type(8))) short bf16x8;   // 8 bf16 (4 VGPR)
typedef __attribute__((ext_vector_type(4))) float f32x4;    // MFMA acc

__device__ __forceinline__ unsigned short f32_to_bf16_rne(float v) {
    unsigned u = __float_as_uint(v);
    return (unsigned short)((u + 0x7FFFu + ((u >> 16) & 1u)) >> 16);
}
__device__ __forceinline__ float bf16_to_f32(unsigned short h) {
    return __uint_as_float(((unsigned)h) << 16);
}
// split v = hi + lo (both bf16), |v-(hi+lo)| ~ 2^-17 |v|
__device__ __forceinline__ void split_bf16(float v, unsigned short& hi, unsigned short& lo) {
    hi = f32_to_bf16_rne(v);
    lo = f32_to_bf16_rne(v - bf16_to_f32(hi));
}
__device__ __forceinline__ unsigned pack_split(float v) {
    unsigned short h, l; split_bf16(v, h, l);
    return (unsigned)h | ((unsigned)l << 16);
}

// ---------------------------------------------------------------------------
// Prep: transpose W1/W2/W3 (W3 padded to 64 cols) into bf16 hi/lo planes.
// Output layout: WT[col][k] (row-major in col), contiguous k.
// ---------------------------------------------------------------------------
__global__ __launch_bounds__(256) void prep_weights(
    const float* __restrict__ W1, const float* __restrict__ W2,
    const float* __restrict__ W3,
    unsigned short* __restrict__ w1hi, unsigned short* __restrict__ w1lo,
    unsigned short* __restrict__ w2hi, unsigned short* __restrict__ w2lo,
    unsigned short* __restrict__ w3hi, unsigned short* __restrict__ w3lo)
{
    const int t = blockIdx.x * 256 + threadIdx.x;   // 0..65535
    {   // W2T: [256][256]
        const int col = t >> 8, k = t & 255;
        unsigned short h, l; split_bf16(W2[(size_t)k*HDIM + col], h, l);
        w2hi[t] = h; w2lo[t] = l;
    }
    if (t < 256*64) {   // W1T: [256 cols][64 k]
        const int col = t >> 6, k = t & 63;
        unsigned short h, l; split_bf16(W1[(size_t)k*HDIM + col], h, l);
        w1hi[t] = h; w1lo[t] = l;
    }
    if (t < N3*256) {   // W3T: [64 cols][256 k], cols >= 49 zero
        const int col = t >> 8, k = t & 255;
        const float v = (col < OUTP) ? W3[(size_t)k*OUTP + col] : 0.f;
        unsigned short h, l; split_bf16(v, h, l);
        w3hi[t] = h; w3lo[t] = l;
    }
}

// ---------------------------------------------------------------------------
// MFMA MLP: 256 blocks x 4 waves, 16 rows/block. Split-bf16 3-MFMA per
// product (~fp32 accuracy). Fragment layouts per verified m89/m92 mapping:
//   A: lane holds A[lane&15][(lane>>4)*8 + j]   (j=0..7)
//   B: lane holds B[(lane>>4)*8 + j][lane&15]   == WT[col][k..k+8)
//   C: col = lane&15, row = (lane>>4)*4 + reg
// Activations carried between layers as packed (hi|lo<<16) u32 in LDS;
// A-frag reads are lane-distributed b128 (no uniform-broadcast reads).
// ---------------------------------------------------------------------------
__global__ __launch_bounds__(256) void mlp_mfma_kernel(
    const float* __restrict__ cond,
    const float* __restrict__ b1, const float* __restrict__ b2,
    const float* __restrict__ b3,
    const unsigned short* __restrict__ w1hi, const unsigned short* __restrict__ w1lo,
    const unsigned short* __restrict__ w2hi, const unsigned short* __restrict__ w2lo,
    const unsigned short* __restrict__ w3hi, const unsigned short* __restrict__ w3lo,
    float* __restrict__ params)
{
    __shared__ unsigned h1c[MROWS][HSTR];   // 16.6 KB packed h1 (hi|lo)
    __shared__ unsigned h2c[MROWS][HSTR];   // 16.6 KB packed h2
    __shared__ float    p_s[MROWS][OUTP];
    __shared__ float    prm_s[MROWS][PSTR];

    const int tid  = threadIdx.x;
    const int lane = tid & 63;
    const int wid  = tid >> 6;        // 0..3
    const int mrow = lane & 15;       // A-row / C-col index
    const int kg   = lane >> 4;       // k-group 0..3
    const int row0 = blockIdx.x * MROWS;

    // ================= layer 1: h1 = relu(cond @ W1 + b1) ==================
    {
        f32x4 acc[4];
        #pragma unroll
        for (int t = 0; t < 4; ++t) acc[t] = (f32x4)0.f;

        #pragma unroll
        for (int c = 0; c < CDIM/32; ++c) {               // 2 K-chunks
            // A-frag from global cond (fp32 -> split)
            const float* ap = cond + (size_t)(row0 + mrow)*CDIM + c*32 + kg*8;
            const float4 a0 = *(const float4*)ap;
            const float4 a1 = *(const float4*)(ap + 4);
            const float av[8] = {a0.x,a0.y,a0.z,a0.w,a1.x,a1.y,a1.z,a1.w};
            bf16x8 Ahi, Alo;
            #pragma unroll
            for (int j = 0; j < 8; ++j) {
                unsigned short h, l; split_bf16(av[j], h, l);
                Ahi[j] = (short)h; Alo[j] = (short)l;
            }
            #pragma unroll
            for (int t = 0; t < 4; ++t) {
                const int colb = wid*64 + t*16 + mrow;
                const size_t off = (size_t)colb*CDIM + c*32 + kg*8;
                const bf16x8 Bhi = *(const bf16x8*)(w1hi + off);
                const bf16x8 Blo = *(const bf16x8*)(w1lo + off);
                acc[t] = __builtin_amdgcn_mfma_f32_16x16x32_bf16(Alo, Bhi, acc[t], 0, 0, 0);
                acc[t] = __builtin_amdgcn_mfma_f32_16x16x32_bf16(Ahi, Blo, acc[t], 0, 0, 0);
                acc[t] = __builtin_amdgcn_mfma_f32_16x16x32_bf16(Ahi, Bhi, acc[t], 0, 0, 0);
            }
        }
        // epilogue: bias + relu -> packed split into h1c
        #pragma unroll
        for (int t = 0; t < 4; ++t) {
            const int col = wid*64 + t*16 + mrow;
            const float bb = b1[col];
            #pragma unroll
            for (int r = 0; r < 4; ++r) {
                const int row = kg*4 + r;
                const float v = fmaxf(acc[t][r] + bb, 0.f);
                h1c[row][col] = pack_split(v);
            }
        }
    }
    __syncthreads();

    // ================= layer 2: h2 = relu(h1 @ W2 + b2) ==================
    {
        f32x4 acc[4];
        #pragma unroll
        for (int t = 0; t < 4; ++t) acc[t] = (f32x4)0.f;

        #pragma unroll 2
        for (int c = 0; c < HDIM/32; ++c) {               // 8 K-chunks
            const uint4 u0 = *(const uint4*)&h1c[mrow][c*32 + kg*8];
            const uint4 u1 = *(const uint4*)&h1c[mrow][c*32 + kg*8 + 4];
            const unsigned uu[8] = {u0.x,u0.y,u0.z,u0.w,u1.x,u1.y,u1.z,u1.w};
            bf16x8 Ahi, Alo;
            #pragma unroll
            for (int j = 0; j < 8; ++j) {
                Ahi[j] = (short)(uu[j] & 0xFFFFu);
                Alo[j] = (short)(uu[j] >> 16);
            }
            #pragma unroll
            for (int t = 0; t < 4; ++t) {
                const int colb = wid*64 + t*16 + mrow;
                const size_t off = (size_t)colb*HDIM + c*32 + kg*8;
                const bf16x8 Bhi = *(const bf16x8*)(w2hi + off);
                const bf16x8 Blo = *(const bf16x8*)(w2lo + off);
                acc[t] = __builtin_amdgcn_mfma_f32_16x16x32_bf16(Alo, Bhi, acc[t], 0, 0, 0);
                acc[t] = __builtin_amdgcn_mfma_f32_16x16x32_bf16(Ahi, Blo, acc[t], 0, 0, 0);
                acc[t] = __builtin_amdgcn_mfma_f32_16x16x32_bf16(Ahi, Bhi, acc[t], 0, 0, 0);
            }
        }
        #pragma unroll
        for (int t = 0; t < 4; ++t) {
            const int col = wid*64 + t*16 + mrow;
            const float bb = b2[col];
            #pragma unroll
            for (int r = 0; r < 4; ++r) {
                const int row = kg*4 + r;
                const float v = fmaxf(acc[t][r] + bb, 0.f);
                h2c[row][col] = pack_split(v);
            }
        }
    }
    __syncthreads();

    // ================= layer 3: p = h2 @ W3 + b3 (cols padded to 64) =======
    {
        f32x4 acc = (f32x4)0.f;
        #pragma unroll 2
        for (int c = 0; c < HDIM/32; ++c) {
            const uint4 u0 = *(const uint4*)&h2c[mrow][c*32 + kg*8];
            const uint4 u1 = *(const uint4*)&h2c[mrow][c*32 + kg*8 + 4];
            const unsigned uu[8] = {u0.x,u0.y,u0.z,u0.w,u1.x,u1.y,u1.z,u1.w};
            bf16x8 Ahi, Alo;
            #pragma unroll
            for (int j = 0; j < 8; ++j) {
                Ahi[j] = (short)(uu[j] & 0xFFFFu);
                Alo[j] = (short)(uu[j] >> 16);
            }
            const int colb = wid*16 + mrow;               // wave = one 16-col tile
            const size_t off = (size_t)colb*HDIM + c*32 + kg*8;
            const bf16x8 Bhi = *(const bf16x8*)(w3hi + off);
            const bf16x8 Blo = *(const bf16x8*)(w3lo + off);
            acc = __builtin_amdgcn_mfma_f32_16x16x32_bf16(Alo, Bhi, acc, 0, 0, 0);
            acc = __builtin_amdgcn_mfma_f32_16x16x32_bf16(Ahi, Blo, acc, 0, 0, 0);
            acc = __builtin_amdgcn_mfma_f32_16x16x32_bf16(Ahi, Bhi, acc, 0, 0, 0);
        }
        const int col = wid*16 + mrow;
        if (col < OUTP) {
            const float bb = b3[col];
            #pragma unroll
            for (int r = 0; r < 4; ++r)
                p_s[kg*4 + r][col] = acc[r] + bb;
        }
    }
    __syncthreads();

    // ---- softmax+cumsum (widths, heights) and softplus (derivs), 16 rows
    if (tid < MROWS*3) {
        const int r   = tid / 3;
        const int seg = tid - 3*r;
        if (seg < 2) {
            const int   off   = (seg == 0) ? 0 : KB;
            const int   cbase = (seg == 0) ? 0 : 17;
            const float mb    = (seg == 0) ? MBW_ : MBH_;
            float m = -1e30f;
            #pragma unroll
            for (int i = 0; i < KB; ++i) m = fmaxf(m, p_s[r][off+i]);
            float e[KB];
            float s = 0.f;
            #pragma unroll
            for (int i = 0; i < KB; ++i) { e[i] = __expf(p_s[r][off+i] - m); s += e[i]; }
            const float span = (2.f*BOUNDF - (float)KB*mb) / s;
            float c = -BOUNDF;
            prm_s[r][cbase] = c;
            #pragma unroll
            for (int i = 0; i < KB; ++i) {
                c += mb + span*e[i];
                prm_s[r][cbase + 1 + i] = c;
            }
        } else {
            #pragma unroll
            for (int i = 0; i < KB+1; ++i) {
                const float x  = p_s[r][2*KB + i];
                const float sp = (x > 20.f) ? x : __logf(1.f + __expf(x));
                prm_s[r][34 + i] = MD_ + sp;
            }
        }
    }
    __syncthreads();

    for (int i = tid; i < MROWS*PSTR; i += 256)
        params[(size_t)row0*PSTR + i] = (&prm_s[0][0])[i];
}

// ---------------------------------------------------------------------------
// Spline application (verbatim R5 best): 4096 blocks, packed 32B bin records
// (1 ds_read_b128 + 1 ds_read_b64 per element), single fast log.
// ---------------------------------------------------------------------------
__global__ __launch_bounds__(256) void spline_kernel(
    const float* __restrict__ y,
    const float* __restrict__ params,
    float* __restrict__ out,
    float* __restrict__ logdet)
{
    __shared__ float prm[PSTR];
    __shared__ float rec[KB][8];
    __shared__ float scan_s[KB];

    const int b   = blockIdx.x;
    const int tid = threadIdx.x;
    if (tid < PSTR) prm[tid] = params[(size_t)b*PSTR + tid];
    __syncthreads();
    if (tid < KB) {
        const int k = tid;
        rec[k][0] = prm[k];        rec[k][1] = prm[k+1];
        rec[k][2] = prm[17+k];     rec[k][3] = prm[17+k+1];
        rec[k][4] = prm[34+k];     rec[k][5] = prm[34+k+1];
        rec[k][6] = 0.f;           rec[k][7] = 0.f;
        scan_s[k] = prm[k+1];      // thresholds cumw[1..16]
    }
    __syncthreads();

    float cw[KB];
    #pragma unroll
    for (int q = 0; q < 4; ++q) {
        const float4 t4 = *(const float4*)&scan_s[4*q];   // uniform broadcast
        cw[4*q+0] = t4.x; cw[4*q+1] = t4.y; cw[4*q+2] = t4.z; cw[4*q+3] = t4.w;
    }

    const size_t base = (size_t)b * NCOL + 4*tid;
    const float4 yv   = *(const float4*)(y + base);
    const float  yy[4] = {yv.x, yv.y, yv.z, yv.w};
    float ov[4], lv[4];

    #pragma unroll
    for (int i = 0; i < 4; ++i) {
        const float yi = yy[i];
        const bool outside = (yi < -BOUNDF) || (yi > BOUNDF);
        const float xc = fminf(fmaxf(yi, -BOUNDF), BOUNDF);
        int bin = 0;
        #pragma unroll
        for (int k = 0; k < KB; ++k) bin += (xc >= cw[k]) ? 1 : 0;
        bin = min(bin, KB-1);

        const float4 lo = *(const float4*)&rec[bin][0];   // ds_read_b128
        const float2 hi = *(const float2*)&rec[bin][4];   // ds_read_b64
        const float w  = lo.y - lo.x;
        const float hh = lo.w - lo.z;
        const float d0 = hi.x, d1 = hi.y;

        const float inv_w = __fdividef(1.f, w);
        const float delta = hh * inv_w;
        const float theta = (xc - lo.x) * inv_w;
        const float omt   = 1.f - theta;
        const float tt    = theta * theta;
        const float tomt  = theta * omt;
        const float num   = hh * (delta*tt + d0*tomt);
        const float den   = delta + (d0 + d1 - 2.f*delta)*tomt;
        const float o     = lo.z + __fdividef(num, den);
        const float der_num = fmaxf(delta*delta*(d1*tt + 2.f*delta*tomt + d0*omt*omt), 1e-12f);
        const float der_den = fmaxf(den*den, 1e-12f);
        const float ld      = __logf(__fdividef(der_num, der_den));

        ov[i] = outside ? yi : o;
        lv[i] = outside ? 0.f : ld;
    }

    *(float4*)(out + base)    = make_float4(ov[0], ov[1], ov[2], ov[3]);
    *(float4*)(logdet + base) = make_float4(lv[0], lv[1], lv[2], lv[3]);
}

extern "C" void kernel_launch(void* const* d_in, const int* in_sizes, int n_in,
                              void* d_out, int out_size, void* d_ws, size_t ws_size,
                              hipStream_t stream) {
    const float* cond = (const float*)d_in[0];
    const float* y    = (const float*)d_in[1];
    const float* W1   = (const float*)d_in[2];
    const float* b1   = (const float*)d_in[3];
    const float* W2   = (const float*)d_in[4];
    const float* b2   = (const float*)d_in[5];
    const float* W3   = (const float*)d_in[6];
    const float* b3   = (const float*)d_in[7];

    float* out    = (float*)d_out;
    float* logdet = out + (size_t)NROW * NCOL;

    // d_ws layout: params (836 KB) @0; bf16 hi/lo transposed weights @1MB.
    float* params = (float*)d_ws;
    unsigned short* w1hi = (unsigned short*)((char*)d_ws + (1 << 20));
    unsigned short* w1lo = w1hi + 64*HDIM;     // 16384
    unsigned short* w2hi = w1lo + 64*HDIM;
    unsigned short* w2lo = w2hi + HDIM*HDIM;   // 65536
    unsigned short* w3hi = w2lo + HDIM*HDIM;
    unsigned short* w3lo = w3hi + N3*HDIM;     // 16384

    prep_weights<<<256, 256, 0, stream>>>(W1, W2, W3, w1hi, w1lo, w2hi, w2lo, w3hi, w3lo);
    mlp_mfma_kernel<<<NROW/MROWS, 256, 0, stream>>>(cond, b1, b2, b3,
                                                    w1hi, w1lo, w2hi, w2lo, w3hi, w3lo,
                                                    params);
    spline_kernel<<<NROW, 256, 0, stream>>>(y, params, out, logdet);
}

// Round 11
// 41.384 us; speedup vs baseline: 1.0247x; 1.0247x over previous
//
#include <hip/hip_runtime.h>
#include <math.h>

namespace {
constexpr int KB    = 16;        // spline bins
constexpr int OUTP  = 3*KB + 1;  // 49
constexpr int CDIM  = 64;
constexpr int HDIM  = 256;
constexpr int NCOL  = 1024;
constexpr int NROW  = 4096;
constexpr float BOUNDF = 5.0f;
constexpr float MBW_ = 0.001f;
constexpr float MBH_ = 0.001f;
constexpr float MD_  = 0.001f;
constexpr int PSTR  = 51;   // 17 cumw | 17 cumh | 17 deriv
constexpr int MROWS = 16;   // rows per MLP block (one 16-row M-tile)
constexpr int HSTR  = 260;  // padded LDS stride (uints)
constexpr int N3    = 64;   // layer-3 cols padded 49 -> 64
// tiled weight-plane sizes (elems): [tiles][chunks][kg:4][mrow:16][j:8]
constexpr int W1E = 16*2*512;   // 16384
constexpr int W2E = 16*8*512;   // 65536
constexpr int W3E = 4*8*512;    // 16384
}

typedef __attribute__((ext_vector_type(8))) short bf16x8;   // 8 bf16 (4 VGPR)
typedef __attribute__((ext_vector_type(4))) float f32x4;    // MFMA acc

__device__ __forceinline__ unsigned short f32_to_bf16_rne(float v) {
    unsigned u = __float_as_uint(v);
    return (unsigned short)((u + 0x7FFFu + ((u >> 16) & 1u)) >> 16);
}
__device__ __forceinline__ float bf16_to_f32(unsigned short h) {
    return __uint_as_float(((unsigned)h) << 16);
}
__device__ __forceinline__ void split_bf16(float v, unsigned short& hi, unsigned short& lo) {
    hi = f32_to_bf16_rne(v);
    lo = f32_to_bf16_rne(v - bf16_to_f32(hi));
}
__device__ __forceinline__ unsigned pack_split(float v) {
    unsigned short h, l; split_bf16(v, h, l);
    return (unsigned)h | ((unsigned)l << 16);
}

// ---------------------------------------------------------------------------
// Prep: WT -> hi/lo bf16 planes in WAVE-TILED layout so the MLP kernel's
// B-frag load is contiguous per wave: idx = (tile*NCHUNK + c)*512 + lane*8,
// where lane = kg*16 + mrow holds B[k=c*32+kg*8+j][col=tile*16+mrow].
// ---------------------------------------------------------------------------
__global__ __launch_bounds__(256) void prep_weights(
    const float* __restrict__ W1, const float* __restrict__ W2,
    const float* __restrict__ W3,
    unsigned short* __restrict__ w1hi, unsigned short* __restrict__ w1lo,
    unsigned short* __restrict__ w2hi, unsigned short* __restrict__ w2lo,
    unsigned short* __restrict__ w3hi, unsigned short* __restrict__ w3lo)
{
    const int t = blockIdx.x * 256 + threadIdx.x;   // 0..65535
    {   // W2: [16 T][8 c][4 kg][16 mrow][8 j]
        const int j = t & 7, mrow = (t>>3)&15, kg = (t>>7)&3, c = (t>>9)&7, T = t>>12;
        const int k = c*32 + kg*8 + j, col = T*16 + mrow;
        unsigned short h, l; split_bf16(W2[(size_t)k*HDIM + col], h, l);
        w2hi[t] = h; w2lo[t] = l;
    }
    if (t < W1E) {   // W1: [16 T][2 c][4 kg][16 mrow][8 j]
        const int j = t & 7, mrow = (t>>3)&15, kg = (t>>7)&3, c = (t>>9)&1, T = t>>10;
        const int k = c*32 + kg*8 + j, col = T*16 + mrow;
        unsigned short h, l; split_bf16(W1[(size_t)k*HDIM + col], h, l);
        w1hi[t] = h; w1lo[t] = l;
    }
    if (t < W3E) {   // W3: [4 T][8 c][4 kg][16 mrow][8 j], cols >= 49 zero
        const int j = t & 7, mrow = (t>>3)&15, kg = (t>>7)&3, c = (t>>9)&7, T = t>>12;
        const int k = c*32 + kg*8 + j, col = T*16 + mrow;
        const float v = (col < OUTP) ? W3[(size_t)k*OUTP + col] : 0.f;
        unsigned short h, l; split_bf16(v, h, l);
        w3hi[t] = h; w3lo[t] = l;
    }
}

// ---------------------------------------------------------------------------
// MFMA MLP (identical math/layout to the PASSING R10 kernel; only the B-frag
// memory layout changed to the coalesced wave-tiled form above).
//   A: lane holds A[lane&15][(lane>>4)*8 + j]
//   B: lane kg*16+mrow holds B[c*32+kg*8+j][T*16+mrow]
//   C: col = lane&15, row = (lane>>4)*4 + reg
// ---------------------------------------------------------------------------
__global__ __launch_bounds__(256) void mlp_mfma_kernel(
    const float* __restrict__ cond,
    const float* __restrict__ b1, const float* __restrict__ b2,
    const float* __restrict__ b3,
    const unsigned short* __restrict__ w1hi, const unsigned short* __restrict__ w1lo,
    const unsigned short* __restrict__ w2hi, const unsigned short* __restrict__ w2lo,
    const unsigned short* __restrict__ w3hi, const unsigned short* __restrict__ w3lo,
    float* __restrict__ params)
{
    __shared__ unsigned h1c[MROWS][HSTR];   // 16.6 KB packed h1 (hi|lo)
    __shared__ unsigned h2c[MROWS][HSTR];   // 16.6 KB packed h2
    __shared__ float    p_s[MROWS][OUTP];
    __shared__ float    prm_s[MROWS][PSTR];

    const int tid  = threadIdx.x;
    const int lane = tid & 63;
    const int wid  = tid >> 6;        // 0..3
    const int mrow = lane & 15;       // A-row / C-col index
    const int kg   = lane >> 4;       // k-group 0..3
    const int row0 = blockIdx.x * MROWS;

    // ================= layer 1: h1 = relu(cond @ W1 + b1) ==================
    {
        f32x4 acc[4];
        #pragma unroll
        for (int t = 0; t < 4; ++t) acc[t] = (f32x4)0.f;

        #pragma unroll
        for (int c = 0; c < CDIM/32; ++c) {               // 2 K-chunks
            const float* ap = cond + (size_t)(row0 + mrow)*CDIM + c*32 + kg*8;
            const float4 a0 = *(const float4*)ap;
            const float4 a1 = *(const float4*)(ap + 4);
            const float av[8] = {a0.x,a0.y,a0.z,a0.w,a1.x,a1.y,a1.z,a1.w};
            bf16x8 Ahi, Alo;
            #pragma unroll
            for (int j = 0; j < 8; ++j) {
                unsigned short h, l; split_bf16(av[j], h, l);
                Ahi[j] = (short)h; Alo[j] = (short)l;
            }
            #pragma unroll
            for (int t = 0; t < 4; ++t) {
                const int T = wid*4 + t;
                const size_t off = (size_t)(T*2 + c)*512 + lane*8;   // coalesced
                const bf16x8 Bhi = *(const bf16x8*)(w1hi + off);
                const bf16x8 Blo = *(const bf16x8*)(w1lo + off);
                acc[t] = __builtin_amdgcn_mfma_f32_16x16x32_bf16(Alo, Bhi, acc[t], 0, 0, 0);
                acc[t] = __builtin_amdgcn_mfma_f32_16x16x32_bf16(Ahi, Blo, acc[t], 0, 0, 0);
                acc[t] = __builtin_amdgcn_mfma_f32_16x16x32_bf16(Ahi, Bhi, acc[t], 0, 0, 0);
            }
        }
        #pragma unroll
        for (int t = 0; t < 4; ++t) {
            const int col = (wid*4 + t)*16 + mrow;
            const float bb = b1[col];
            #pragma unroll
            for (int r = 0; r < 4; ++r) {
                const int row = kg*4 + r;
                const float v = fmaxf(acc[t][r] + bb, 0.f);
                h1c[row][col] = pack_split(v);
            }
        }
    }
    __syncthreads();

    // ================= layer 2: h2 = relu(h1 @ W2 + b2) ==================
    {
        f32x4 acc[4];
        #pragma unroll
        for (int t = 0; t < 4; ++t) acc[t] = (f32x4)0.f;

        #pragma unroll 2
        for (int c = 0; c < HDIM/32; ++c) {               // 8 K-chunks
            const uint4 u0 = *(const uint4*)&h1c[mrow][c*32 + kg*8];
            const uint4 u1 = *(const uint4*)&h1c[mrow][c*32 + kg*8 + 4];
            const unsigned uu[8] = {u0.x,u0.y,u0.z,u0.w,u1.x,u1.y,u1.z,u1.w};
            bf16x8 Ahi, Alo;
            #pragma unroll
            for (int j = 0; j < 8; ++j) {
                Ahi[j] = (short)(uu[j] & 0xFFFFu);
                Alo[j] = (short)(uu[j] >> 16);
            }
            #pragma unroll
            for (int t = 0; t < 4; ++t) {
                const int T = wid*4 + t;
                const size_t off = (size_t)(T*8 + c)*512 + lane*8;   // coalesced
                const bf16x8 Bhi = *(const bf16x8*)(w2hi + off);
                const bf16x8 Blo = *(const bf16x8*)(w2lo + off);
                acc[t] = __builtin_amdgcn_mfma_f32_16x16x32_bf16(Alo, Bhi, acc[t], 0, 0, 0);
                acc[t] = __builtin_amdgcn_mfma_f32_16x16x32_bf16(Ahi, Blo, acc[t], 0, 0, 0);
                acc[t] = __builtin_amdgcn_mfma_f32_16x16x32_bf16(Ahi, Bhi, acc[t], 0, 0, 0);
            }
        }
        #pragma unroll
        for (int t = 0; t < 4; ++t) {
            const int col = (wid*4 + t)*16 + mrow;
            const float bb = b2[col];
            #pragma unroll
            for (int r = 0; r < 4; ++r) {
                const int row = kg*4 + r;
                const float v = fmaxf(acc[t][r] + bb, 0.f);
                h2c[row][col] = pack_split(v);
            }
        }
    }
    __syncthreads();

    // ================= layer 3: p = h2 @ W3 + b3 (cols padded to 64) =======
    {
        f32x4 acc = (f32x4)0.f;
        #pragma unroll 2
        for (int c = 0; c < HDIM/32; ++c) {
            const uint4 u0 = *(const uint4*)&h2c[mrow][c*32 + kg*8];
            const uint4 u1 = *(const uint4*)&h2c[mrow][c*32 + kg*8 + 4];
            const unsigned uu[8] = {u0.x,u0.y,u0.z,u0.w,u1.x,u1.y,u1.z,u1.w};
            bf16x8 Ahi, Alo;
            #pragma unroll
            for (int j = 0; j < 8; ++j) {
                Ahi[j] = (short)(uu[j] & 0xFFFFu);
                Alo[j] = (short)(uu[j] >> 16);
            }
            const size_t off = (size_t)(wid*8 + c)*512 + lane*8;     // coalesced
            const bf16x8 Bhi = *(const bf16x8*)(w3hi + off);
            const bf16x8 Blo = *(const bf16x8*)(w3lo + off);
            acc = __builtin_amdgcn_mfma_f32_16x16x32_bf16(Alo, Bhi, acc, 0, 0, 0);
            acc = __builtin_amdgcn_mfma_f32_16x16x32_bf16(Ahi, Blo, acc, 0, 0, 0);
            acc = __builtin_amdgcn_mfma_f32_16x16x32_bf16(Ahi, Bhi, acc, 0, 0, 0);
        }
        const int col = wid*16 + mrow;
        if (col < OUTP) {
            const float bb = b3[col];
            #pragma unroll
            for (int r = 0; r < 4; ++r)
                p_s[kg*4 + r][col] = acc[r] + bb;
        }
    }
    __syncthreads();

    // ---- softmax+cumsum (widths, heights) and softplus (derivs), 16 rows
    if (tid < MROWS*3) {
        const int r   = tid / 3;
        const int seg = tid - 3*r;
        if (seg < 2) {
            const int   off   = (seg == 0) ? 0 : KB;
            const int   cbase = (seg == 0) ? 0 : 17;
            const float mb    = (seg == 0) ? MBW_ : MBH_;
            float m = -1e30f;
            #pragma unroll
            for (int i = 0; i < KB; ++i) m = fmaxf(m, p_s[r][off+i]);
            float e[KB];
            float s = 0.f;
            #pragma unroll
            for (int i = 0; i < KB; ++i) { e[i] = __expf(p_s[r][off+i] - m); s += e[i]; }
            const float span = (2.f*BOUNDF - (float)KB*mb) / s;
            float c = -BOUNDF;
            prm_s[r][cbase] = c;
            #pragma unroll
            for (int i = 0; i < KB; ++i) {
                c += mb + span*e[i];
                prm_s[r][cbase + 1 + i] = c;
            }
        } else {
            #pragma unroll
            for (int i = 0; i < KB+1; ++i) {
                const float x  = p_s[r][2*KB + i];
                const float sp = (x > 20.f) ? x : __logf(1.f + __expf(x));
                prm_s[r][34 + i] = MD_ + sp;
            }
        }
    }
    __syncthreads();

    for (int i = tid; i < MROWS*PSTR; i += 256)
        params[(size_t)row0*PSTR + i] = (&prm_s[0][0])[i];
}

// ---------------------------------------------------------------------------
// Spline application (verbatim R5 best): 4096 blocks, packed 32B bin records
// (1 ds_read_b128 + 1 ds_read_b64 per element), single fast log.
// ---------------------------------------------------------------------------
__global__ __launch_bounds__(256) void spline_kernel(
    const float* __restrict__ y,
    const float* __restrict__ params,
    float* __restrict__ out,
    float* __restrict__ logdet)
{
    __shared__ float prm[PSTR];
    __shared__ float rec[KB][8];
    __shared__ float scan_s[KB];

    const int b   = blockIdx.x;
    const int tid = threadIdx.x;
    if (tid < PSTR) prm[tid] = params[(size_t)b*PSTR + tid];
    __syncthreads();
    if (tid < KB) {
        const int k = tid;
        rec[k][0] = prm[k];        rec[k][1] = prm[k+1];
        rec[k][2] = prm[17+k];     rec[k][3] = prm[17+k+1];
        rec[k][4] = prm[34+k];     rec[k][5] = prm[34+k+1];
        rec[k][6] = 0.f;           rec[k][7] = 0.f;
        scan_s[k] = prm[k+1];      // thresholds cumw[1..16]
    }
    __syncthreads();

    float cw[KB];
    #pragma unroll
    for (int q = 0; q < 4; ++q) {
        const float4 t4 = *(const float4*)&scan_s[4*q];   // uniform broadcast
        cw[4*q+0] = t4.x; cw[4*q+1] = t4.y; cw[4*q+2] = t4.z; cw[4*q+3] = t4.w;
    }

    const size_t base = (size_t)b * NCOL + 4*tid;
    const float4 yv   = *(const float4*)(y + base);
    const float  yy[4] = {yv.x, yv.y, yv.z, yv.w};
    float ov[4], lv[4];

    #pragma unroll
    for (int i = 0; i < 4; ++i) {
        const float yi = yy[i];
        const bool outside = (yi < -BOUNDF) || (yi > BOUNDF);
        const float xc = fminf(fmaxf(yi, -BOUNDF), BOUNDF);
        int bin = 0;
        #pragma unroll
        for (int k = 0; k < KB; ++k) bin += (xc >= cw[k]) ? 1 : 0;
        bin = min(bin, KB-1);

        const float4 lo = *(const float4*)&rec[bin][0];   // ds_read_b128
        const float2 hi = *(const float2*)&rec[bin][4];   // ds_read_b64
        const float w  = lo.y - lo.x;
        const float hh = lo.w - lo.z;
        const float d0 = hi.x, d1 = hi.y;

        const float inv_w = __fdividef(1.f, w);
        const float delta = hh * inv_w;
        const float theta = (xc - lo.x) * inv_w;
        const float omt   = 1.f - theta;
        const float tt    = theta * theta;
        const float tomt  = theta * omt;
        const float num   = hh * (delta*tt + d0*tomt);
        const float den   = delta + (d0 + d1 - 2.f*delta)*tomt;
        const float o     = lo.z + __fdividef(num, den);
        const float der_num = fmaxf(delta*delta*(d1*tt + 2.f*delta*tomt + d0*omt*omt), 1e-12f);
        const float der_den = fmaxf(den*den, 1e-12f);
        const float ld      = __logf(__fdividef(der_num, der_den));

        ov[i] = outside ? yi : o;
        lv[i] = outside ? 0.f : ld;
    }

    *(float4*)(out + base)    = make_float4(ov[0], ov[1], ov[2], ov[3]);
    *(float4*)(logdet + base) = make_float4(lv[0], lv[1], lv[2], lv[3]);
}

extern "C" void kernel_launch(void* const* d_in, const int* in_sizes, int n_in,
                              void* d_out, int out_size, void* d_ws, size_t ws_size,
                              hipStream_t stream) {
    const float* cond = (const float*)d_in[0];
    const float* y    = (const float*)d_in[1];
    const float* W1   = (const float*)d_in[2];
    const float* b1   = (const float*)d_in[3];
    const float* W2   = (const float*)d_in[4];
    const float* b2   = (const float*)d_in[5];
    const float* W3   = (const float*)d_in[6];
    const float* b3   = (const float*)d_in[7];

    float* out    = (float*)d_out;
    float* logdet = out + (size_t)NROW * NCOL;

    // d_ws layout: params (836 KB) @0; tiled bf16 hi/lo weights @1MB.
    float* params = (float*)d_ws;
    unsigned short* w1hi = (unsigned short*)((char*)d_ws + (1 << 20));
    unsigned short* w1lo = w1hi + W1E;
    unsigned short* w2hi = w1lo + W1E;
    unsigned short* w2lo = w2hi + W2E;
    unsigned short* w3hi = w2lo + W2E;
    unsigned short* w3lo = w3hi + W3E;

    prep_weights<<<256, 256, 0, stream>>>(W1, W2, W3, w1hi, w1lo, w2hi, w2lo, w3hi, w3lo);
    mlp_mfma_kernel<<<NROW/MROWS, 256, 0, stream>>>(cond, b1, b2, b3,
                                                    w1hi, w1lo, w2hi, w2lo, w3hi, w3lo,
                                                    params);
    spline_kernel<<<NROW, 256, 0, stream>>>(y, params, out, logdet);
}

// Round 12
// 38.512 us; speedup vs baseline: 1.1011x; 1.0746x over previous
//
#include <hip/hip_runtime.h>
#include <math.h>

namespace {
constexpr int KB    = 16;        // spline bins
constexpr int OUTP  = 3*KB + 1;  // 49
constexpr int CDIM  = 64;
constexpr int HDIM  = 256;
constexpr int NCOL  = 1024;
constexpr int NROW  = 4096;
constexpr float BOUNDF = 5.0f;
constexpr float MBW_ = 0.001f;
constexpr float MBH_ = 0.001f;
constexpr float MD_  = 0.001f;
constexpr int PSTR  = 51;   // 17 cumw | 17 cumh | 17 deriv
constexpr int MROWS = 16;   // rows per block (one 16-row M-tile)
constexpr int HSTR  = 260;  // padded LDS stride (uints)
// tiled weight-plane sizes (elems): [tiles][chunks][kg:4][mrow:16][j:8]
constexpr int W1E = 16*2*512;   // 16384
constexpr int W2E = 16*8*512;   // 65536
constexpr int W3E = 4*8*512;    // 16384
}

typedef __attribute__((ext_vector_type(8))) short bf16x8;   // 8 bf16 (4 VGPR)
typedef __attribute__((ext_vector_type(4))) float f32x4;    // MFMA acc

__device__ __forceinline__ unsigned short f32_to_bf16_rne(float v) {
    unsigned u = __float_as_uint(v);
    return (unsigned short)((u + 0x7FFFu + ((u >> 16) & 1u)) >> 16);
}
__device__ __forceinline__ float bf16_to_f32(unsigned short h) {
    return __uint_as_float(((unsigned)h) << 16);
}
__device__ __forceinline__ void split_bf16(float v, unsigned short& hi, unsigned short& lo) {
    hi = f32_to_bf16_rne(v);
    lo = f32_to_bf16_rne(v - bf16_to_f32(hi));
}
__device__ __forceinline__ unsigned pack_split(float v) {
    unsigned short h, l; split_bf16(v, h, l);
    return (unsigned)h | ((unsigned)l << 16);
}

// ---------------------------------------------------------------------------
// Prep (unchanged, proven): WT -> hi/lo bf16 planes, wave-tiled layout:
// idx = (tile*NCHUNK + c)*512 + lane*8, lane = kg*16 + mrow holds
// B[k=c*32+kg*8+j][col=tile*16+mrow].
// ---------------------------------------------------------------------------
__global__ __launch_bounds__(256) void prep_weights(
    const float* __restrict__ W1, const float* __restrict__ W2,
    const float* __restrict__ W3,
    unsigned short* __restrict__ w1hi, unsigned short* __restrict__ w1lo,
    unsigned short* __restrict__ w2hi, unsigned short* __restrict__ w2lo,
    unsigned short* __restrict__ w3hi, unsigned short* __restrict__ w3lo)
{
    const int t = blockIdx.x * 256 + threadIdx.x;   // 0..65535
    {   // W2: [16 T][8 c][4 kg][16 mrow][8 j]
        const int j = t & 7, mrow = (t>>3)&15, kg = (t>>7)&3, c = (t>>9)&7, T = t>>12;
        const int k = c*32 + kg*8 + j, col = T*16 + mrow;
        unsigned short h, l; split_bf16(W2[(size_t)k*HDIM + col], h, l);
        w2hi[t] = h; w2lo[t] = l;
    }
    if (t < W1E) {   // W1: [16 T][2 c][4 kg][16 mrow][8 j]
        const int j = t & 7, mrow = (t>>3)&15, kg = (t>>7)&3, c = (t>>9)&1, T = t>>10;
        const int k = c*32 + kg*8 + j, col = T*16 + mrow;
        unsigned short h, l; split_bf16(W1[(size_t)k*HDIM + col], h, l);
        w1hi[t] = h; w1lo[t] = l;
    }
    if (t < W3E) {   // W3: [4 T][8 c][4 kg][16 mrow][8 j], cols >= 49 zero
        const int j = t & 7, mrow = (t>>3)&15, kg = (t>>7)&3, c = (t>>9)&7, T = t>>12;
        const int k = c*32 + kg*8 + j, col = T*16 + mrow;
        const float v = (col < OUTP) ? W3[(size_t)k*OUTP + col] : 0.f;
        unsigned short h, l; split_bf16(v, h, l);
        w3hi[t] = h; w3lo[t] = l;
    }
}

// ---------------------------------------------------------------------------
// Fused: MFMA MLP (8 waves; verified R10/R11 fragment maps) -> spline params
// in LDS -> stream 16 rows of y (8 passes x 2 rows, coalesced float4).
// No params round-trip; 2 total launches in the graph.
//   A: lane holds A[lane&15][(lane>>4)*8 + j]
//   B: lane kg*16+mrow holds B[c*32+kg*8+j][T*16+mrow]  (wave-tiled planes)
//   C: col = lane&15, row = (lane>>4)*4 + reg
// ---------------------------------------------------------------------------
__global__ __launch_bounds__(512) void fused_mfma_spline(
    const float* __restrict__ cond, const float* __restrict__ y,
    const float* __restrict__ b1, const float* __restrict__ b2,
    const float* __restrict__ b3,
    const unsigned short* __restrict__ w1hi, const unsigned short* __restrict__ w1lo,
    const unsigned short* __restrict__ w2hi, const unsigned short* __restrict__ w2lo,
    const unsigned short* __restrict__ w3hi, const unsigned short* __restrict__ w3lo,
    float* __restrict__ out, float* __restrict__ logdet)
{
    __shared__ unsigned h1c[MROWS][HSTR];   // 16.6 KB packed h1 (hi|lo)
    __shared__ unsigned h2c[MROWS][HSTR];   // 16.6 KB packed h2
    __shared__ float    p_s[MROWS][OUTP];   //  3.1 KB
    __shared__ float    prm_s[MROWS][PSTR]; //  3.3 KB
    __shared__ float    rec[MROWS][KB][8];  //  8   KB packed bin records
    __shared__ float    scan_s[MROWS][16];  //  1   KB thresholds

    const int tid  = threadIdx.x;
    const int lane = tid & 63;
    const int wid  = tid >> 6;        // 0..7
    const int mrow = lane & 15;
    const int kg   = lane >> 4;
    const int row0 = blockIdx.x * MROWS;

    // ================= layer 1: h1 = relu(cond @ W1 + b1) ==================
    {
        f32x4 acc[2];
        acc[0] = (f32x4)0.f; acc[1] = (f32x4)0.f;
        #pragma unroll
        for (int c = 0; c < CDIM/32; ++c) {
            const float* ap = cond + (size_t)(row0 + mrow)*CDIM + c*32 + kg*8;
            const float4 a0 = *(const float4*)ap;
            const float4 a1 = *(const float4*)(ap + 4);
            const float av[8] = {a0.x,a0.y,a0.z,a0.w,a1.x,a1.y,a1.z,a1.w};
            bf16x8 Ahi, Alo;
            #pragma unroll
            for (int j = 0; j < 8; ++j) {
                unsigned short h, l; split_bf16(av[j], h, l);
                Ahi[j] = (short)h; Alo[j] = (short)l;
            }
            #pragma unroll
            for (int t = 0; t < 2; ++t) {
                const int T = 2*wid + t;
                const size_t off = (size_t)(T*2 + c)*512 + lane*8;
                const bf16x8 Bhi = *(const bf16x8*)(w1hi + off);
                const bf16x8 Blo = *(const bf16x8*)(w1lo + off);
                acc[t] = __builtin_amdgcn_mfma_f32_16x16x32_bf16(Alo, Bhi, acc[t], 0, 0, 0);
                acc[t] = __builtin_amdgcn_mfma_f32_16x16x32_bf16(Ahi, Blo, acc[t], 0, 0, 0);
                acc[t] = __builtin_amdgcn_mfma_f32_16x16x32_bf16(Ahi, Bhi, acc[t], 0, 0, 0);
            }
        }
        #pragma unroll
        for (int t = 0; t < 2; ++t) {
            const int col = (2*wid + t)*16 + mrow;
            const float bb = b1[col];
            #pragma unroll
            for (int r = 0; r < 4; ++r)
                h1c[kg*4 + r][col] = pack_split(fmaxf(acc[t][r] + bb, 0.f));
        }
    }
    __syncthreads();

    // ================= layer 2: h2 = relu(h1 @ W2 + b2) ==================
    {
        f32x4 acc[2];
        acc[0] = (f32x4)0.f; acc[1] = (f32x4)0.f;
        #pragma unroll 2
        for (int c = 0; c < HDIM/32; ++c) {
            const uint4 u0 = *(const uint4*)&h1c[mrow][c*32 + kg*8];
            const uint4 u1 = *(const uint4*)&h1c[mrow][c*32 + kg*8 + 4];
            const unsigned uu[8] = {u0.x,u0.y,u0.z,u0.w,u1.x,u1.y,u1.z,u1.w};
            bf16x8 Ahi, Alo;
            #pragma unroll
            for (int j = 0; j < 8; ++j) {
                Ahi[j] = (short)(uu[j] & 0xFFFFu);
                Alo[j] = (short)(uu[j] >> 16);
            }
            #pragma unroll
            for (int t = 0; t < 2; ++t) {
                const int T = 2*wid + t;
                const size_t off = (size_t)(T*8 + c)*512 + lane*8;
                const bf16x8 Bhi = *(const bf16x8*)(w2hi + off);
                const bf16x8 Blo = *(const bf16x8*)(w2lo + off);
                acc[t] = __builtin_amdgcn_mfma_f32_16x16x32_bf16(Alo, Bhi, acc[t], 0, 0, 0);
                acc[t] = __builtin_amdgcn_mfma_f32_16x16x32_bf16(Ahi, Blo, acc[t], 0, 0, 0);
                acc[t] = __builtin_amdgcn_mfma_f32_16x16x32_bf16(Ahi, Bhi, acc[t], 0, 0, 0);
            }
        }
        #pragma unroll
        for (int t = 0; t < 2; ++t) {
            const int col = (2*wid + t)*16 + mrow;
            const float bb = b2[col];
            #pragma unroll
            for (int r = 0; r < 4; ++r)
                h2c[kg*4 + r][col] = pack_split(fmaxf(acc[t][r] + bb, 0.f));
        }
    }
    __syncthreads();

    // ================= layer 3: p = h2 @ W3 + b3 (waves 0-3) ===============
    if (wid < 4) {
        f32x4 acc = (f32x4)0.f;
        #pragma unroll 2
        for (int c = 0; c < HDIM/32; ++c) {
            const uint4 u0 = *(const uint4*)&h2c[mrow][c*32 + kg*8];
            const uint4 u1 = *(const uint4*)&h2c[mrow][c*32 + kg*8 + 4];
            const unsigned uu[8] = {u0.x,u0.y,u0.z,u0.w,u1.x,u1.y,u1.z,u1.w};
            bf16x8 Ahi, Alo;
            #pragma unroll
            for (int j = 0; j < 8; ++j) {
                Ahi[j] = (short)(uu[j] & 0xFFFFu);
                Alo[j] = (short)(uu[j] >> 16);
            }
            const size_t off = (size_t)(wid*8 + c)*512 + lane*8;
            const bf16x8 Bhi = *(const bf16x8*)(w3hi + off);
            const bf16x8 Blo = *(const bf16x8*)(w3lo + off);
            acc = __builtin_amdgcn_mfma_f32_16x16x32_bf16(Alo, Bhi, acc, 0, 0, 0);
            acc = __builtin_amdgcn_mfma_f32_16x16x32_bf16(Ahi, Blo, acc, 0, 0, 0);
            acc = __builtin_amdgcn_mfma_f32_16x16x32_bf16(Ahi, Bhi, acc, 0, 0, 0);
        }
        const int col = wid*16 + mrow;
        if (col < OUTP) {
            const float bb = b3[col];
            #pragma unroll
            for (int r = 0; r < 4; ++r)
                p_s[kg*4 + r][col] = acc[r] + bb;
        }
    }
    __syncthreads();

    // ---- softmax+cumsum / softplus -> prm_s (16 rows x 3 tasks)
    if (tid < MROWS*3) {
        const int r   = tid / 3;
        const int seg = tid - 3*r;
        if (seg < 2) {
            const int   off   = (seg == 0) ? 0 : KB;
            const int   cbase = (seg == 0) ? 0 : 17;
            const float mb    = (seg == 0) ? MBW_ : MBH_;
            float m = -1e30f;
            #pragma unroll
            for (int i = 0; i < KB; ++i) m = fmaxf(m, p_s[r][off+i]);
            float e[KB];
            float s = 0.f;
            #pragma unroll
            for (int i = 0; i < KB; ++i) { e[i] = __expf(p_s[r][off+i] - m); s += e[i]; }
            const float span = (2.f*BOUNDF - (float)KB*mb) / s;
            float c = -BOUNDF;
            prm_s[r][cbase] = c;
            #pragma unroll
            for (int i = 0; i < KB; ++i) {
                c += mb + span*e[i];
                prm_s[r][cbase + 1 + i] = c;
            }
        } else {
            #pragma unroll
            for (int i = 0; i < KB+1; ++i) {
                const float x  = p_s[r][2*KB + i];
                const float sp = (x > 20.f) ? x : __logf(1.f + __expf(x));
                prm_s[r][34 + i] = MD_ + sp;
            }
        }
    }
    __syncthreads();

    // ---- build packed 32B bin records + thresholds (16 rows x 16 bins)
    if (tid < MROWS*KB) {
        const int r = tid >> 4;
        const int k = tid & 15;
        rec[r][k][0] = prm_s[r][k];        rec[r][k][1] = prm_s[r][k+1];
        rec[r][k][2] = prm_s[r][17+k];     rec[r][k][3] = prm_s[r][17+k+1];
        rec[r][k][4] = prm_s[r][34+k];     rec[r][k][5] = prm_s[r][34+k+1];
        rec[r][k][6] = 0.f;                rec[r][k][7] = 0.f;
        scan_s[r][k] = prm_s[r][k+1];
    }
    __syncthreads();

    // ================= spline: 8 passes x 2 rows (512 thr, float4 I/O) =====
    const int rowp = tid >> 8;              // 0/1: row within pass
    const int col0 = (tid & 255) * 4;

    float4 yv[8];
    #pragma unroll
    for (int p = 0; p < 8; ++p)             // independent loads, issued early
        yv[p] = *(const float4*)(y + (size_t)(row0 + 2*p + rowp)*NCOL + col0);

    #pragma unroll
    for (int p = 0; p < 8; ++p) {
        const int r = 2*p + rowp;
        float cw[KB];
        #pragma unroll
        for (int q = 0; q < 4; ++q) {
            const float4 t4 = *(const float4*)&scan_s[r][4*q];
            cw[4*q+0] = t4.x; cw[4*q+1] = t4.y; cw[4*q+2] = t4.z; cw[4*q+3] = t4.w;
        }
        const float yy[4] = {yv[p].x, yv[p].y, yv[p].z, yv[p].w};
        float ov[4], lv[4];
        #pragma unroll
        for (int i = 0; i < 4; ++i) {
            const float yi = yy[i];
            const bool outside = (yi < -BOUNDF) || (yi > BOUNDF);
            const float xc = fminf(fmaxf(yi, -BOUNDF), BOUNDF);
            int bin = 0;
            #pragma unroll
            for (int k = 0; k < KB; ++k) bin += (xc >= cw[k]) ? 1 : 0;
            bin = min(bin, KB-1);

            const float4 lo = *(const float4*)&rec[r][bin][0];  // ds_read_b128
            const float2 hi = *(const float2*)&rec[r][bin][4];  // ds_read_b64
            const float w  = lo.y - lo.x;
            const float hh = lo.w - lo.z;
            const float d0 = hi.x, d1 = hi.y;

            const float inv_w = __fdividef(1.f, w);
            const float delta = hh * inv_w;
            const float theta = (xc - lo.x) * inv_w;
            const float omt   = 1.f - theta;
            const float tt    = theta * theta;
            const float tomt  = theta * omt;
            const float num   = hh * (delta*tt + d0*tomt);
            const float den   = delta + (d0 + d1 - 2.f*delta)*tomt;
            const float o     = lo.z + __fdividef(num, den);
            const float der_num = fmaxf(delta*delta*(d1*tt + 2.f*delta*tomt + d0*omt*omt), 1e-12f);
            const float der_den = fmaxf(den*den, 1e-12f);
            const float ld      = __logf(__fdividef(der_num, der_den));

            ov[i] = outside ? yi : o;
            lv[i] = outside ? 0.f : ld;
        }
        const size_t base = (size_t)(row0 + r)*NCOL + col0;
        *(float4*)(out + base)    = make_float4(ov[0], ov[1], ov[2], ov[3]);
        *(float4*)(logdet + base) = make_float4(lv[0], lv[1], lv[2], lv[3]);
    }
}

extern "C" void kernel_launch(void* const* d_in, const int* in_sizes, int n_in,
                              void* d_out, int out_size, void* d_ws, size_t ws_size,
                              hipStream_t stream) {
    const float* cond = (const float*)d_in[0];
    const float* y    = (const float*)d_in[1];
    const float* W1   = (const float*)d_in[2];
    const float* b1   = (const float*)d_in[3];
    const float* W2   = (const float*)d_in[4];
    const float* b2   = (const float*)d_in[5];
    const float* W3   = (const float*)d_in[6];
    const float* b3   = (const float*)d_in[7];

    float* out    = (float*)d_out;
    float* logdet = out + (size_t)NROW * NCOL;

    // d_ws: tiled bf16 hi/lo weight planes only (no params round-trip).
    unsigned short* w1hi = (unsigned short*)d_ws;
    unsigned short* w1lo = w1hi + W1E;
    unsigned short* w2hi = w1lo + W1E;
    unsigned short* w2lo = w2hi + W2E;
    unsigned short* w3hi = w2lo + W2E;
    unsigned short* w3lo = w3hi + W3E;

    prep_weights<<<256, 256, 0, stream>>>(W1, W2, W3, w1hi, w1lo, w2hi, w2lo, w3hi, w3lo);
    fused_mfma_spline<<<NROW/MROWS, 512, 0, stream>>>(cond, y, b1, b2, b3,
                                                      w1hi, w1lo, w2hi, w2lo, w3hi, w3lo,
                                                      out, logdet);
}

// Round 13
// 37.250 us; speedup vs baseline: 1.1384x; 1.0339x over previous
//
#include <hip/hip_runtime.h>
#include <math.h>

namespace {
constexpr int KB    = 16;        // spline bins
constexpr int OUTP  = 3*KB + 1;  // 49
constexpr int CDIM  = 64;
constexpr int HDIM  = 256;
constexpr int NCOL  = 1024;
constexpr int NROW  = 4096;
constexpr float BOUNDF = 5.0f;
constexpr float MBW_ = 0.001f;
constexpr float MBH_ = 0.001f;
constexpr float MD_  = 0.001f;
constexpr int PSTR  = 51;   // 17 cumw | 17 cumh | 17 deriv
constexpr int MROWS = 16;   // rows per MLP block
constexpr int HSTR  = 260;  // padded LDS stride (uints)
// tiled weight-plane sizes (elems): [tiles][chunks][kg:4][mrow:16][j:8]
constexpr int W1E = 16*2*512;   // 16384
constexpr int W2E = 16*8*512;   // 65536
constexpr int W3E = 4*8*512;    // 16384
}

typedef __attribute__((ext_vector_type(8))) short bf16x8;   // 8 bf16 (4 VGPR)
typedef __attribute__((ext_vector_type(4))) float f32x4;    // MFMA acc

__device__ __forceinline__ unsigned short f32_to_bf16_rne(float v) {
    unsigned u = __float_as_uint(v);
    return (unsigned short)((u + 0x7FFFu + ((u >> 16) & 1u)) >> 16);
}
__device__ __forceinline__ float bf16_to_f32(unsigned short h) {
    return __uint_as_float(((unsigned)h) << 16);
}
__device__ __forceinline__ void split_bf16(float v, unsigned short& hi, unsigned short& lo) {
    hi = f32_to_bf16_rne(v);
    lo = f32_to_bf16_rne(v - bf16_to_f32(hi));
}
__device__ __forceinline__ unsigned pack_split(float v) {
    unsigned short h, l; split_bf16(v, h, l);
    return (unsigned)h | ((unsigned)l << 16);
}

// tiled index for B-planes: from (k, col) -> [T][c][kg][mrow][j]
__device__ __forceinline__ int tiled_idx(int k, int col, int nchunk) {
    const int c = k >> 5, kg = (k >> 3) & 3, j = k & 7;
    const int T = col >> 4, mrow = col & 15;
    return ((T*nchunk + c) << 9) + (kg << 7) + (mrow << 3) + j;
}

// ---------------------------------------------------------------------------
// Prep: coalesced READS (sequential source index), scattered 2B stores into
// the wave-tiled layout (8 cache lines/wave vs 64 for scattered reads).
// ---------------------------------------------------------------------------
__global__ __launch_bounds__(256) void prep_weights(
    const float* __restrict__ W1, const float* __restrict__ W2,
    const float* __restrict__ W3,
    unsigned short* __restrict__ w1hi, unsigned short* __restrict__ w1lo,
    unsigned short* __restrict__ w2hi, unsigned short* __restrict__ w2lo,
    unsigned short* __restrict__ w3hi, unsigned short* __restrict__ w3lo)
{
    const int t = blockIdx.x * 256 + threadIdx.x;   // 0..65535
    {   // W2: source order k*256+col (coalesced read)
        const int k = t >> 8, col = t & 255;
        unsigned short h, l; split_bf16(W2[t], h, l);
        const int d = tiled_idx(k, col, 8);
        w2hi[d] = h; w2lo[d] = l;
    }
    if (t < W1E) {   // W1: [64 k][256 col]
        const int k = t >> 8, col = t & 255;
        unsigned short h, l; split_bf16(W1[t], h, l);
        const int d = tiled_idx(k, col, 2);
        w1hi[d] = h; w1lo[d] = l;
    }
    if (t < W3E) {   // W3 padded [256 k][64 col]; cols >= 49 zero
        const int k = t >> 6, col = t & 63;
        const float v = (col < OUTP) ? W3[(size_t)k*OUTP + col] : 0.f;
        unsigned short h, l; split_bf16(v, h, l);
        const int d = tiled_idx(k, col, 8);
        w3hi[d] = h; w3lo[d] = l;
    }
}

// ---------------------------------------------------------------------------
// MFMA MLP, 8 waves (R12's verified fused-MLP code; wave w owns col-tiles
// 2w, 2w+1; layer 3 on waves 0-3) -> params in d_ws. 256 blocks x 512 thr,
// ~37 KB LDS. 2 waves/SIMD halves the latency exposure vs R11's 4-wave.
//   A: lane holds A[lane&15][(lane>>4)*8 + j]
//   B: lane kg*16+mrow holds B[c*32+kg*8+j][T*16+mrow]  (wave-tiled planes)
//   C: col = lane&15, row = (lane>>4)*4 + reg
// ---------------------------------------------------------------------------
__global__ __launch_bounds__(512) void mlp_mfma_kernel(
    const float* __restrict__ cond,
    const float* __restrict__ b1, const float* __restrict__ b2,
    const float* __restrict__ b3,
    const unsigned short* __restrict__ w1hi, const unsigned short* __restrict__ w1lo,
    const unsigned short* __restrict__ w2hi, const unsigned short* __restrict__ w2lo,
    const unsigned short* __restrict__ w3hi, const unsigned short* __restrict__ w3lo,
    float* __restrict__ params)
{
    __shared__ unsigned h1c[MROWS][HSTR];   // 16.6 KB packed h1 (hi|lo)
    __shared__ unsigned h2c[MROWS][HSTR];   // 16.6 KB packed h2
    __shared__ float    p_s[MROWS][OUTP];
    __shared__ float    prm_s[MROWS][PSTR];

    const int tid  = threadIdx.x;
    const int lane = tid & 63;
    const int wid  = tid >> 6;        // 0..7
    const int mrow = lane & 15;
    const int kg   = lane >> 4;
    const int row0 = blockIdx.x * MROWS;

    // ================= layer 1: h1 = relu(cond @ W1 + b1) ==================
    {
        f32x4 acc[2];
        acc[0] = (f32x4)0.f; acc[1] = (f32x4)0.f;
        #pragma unroll
        for (int c = 0; c < CDIM/32; ++c) {
            const float* ap = cond + (size_t)(row0 + mrow)*CDIM + c*32 + kg*8;
            const float4 a0 = *(const float4*)ap;
            const float4 a1 = *(const float4*)(ap + 4);
            const float av[8] = {a0.x,a0.y,a0.z,a0.w,a1.x,a1.y,a1.z,a1.w};
            bf16x8 Ahi, Alo;
            #pragma unroll
            for (int j = 0; j < 8; ++j) {
                unsigned short h, l; split_bf16(av[j], h, l);
                Ahi[j] = (short)h; Alo[j] = (short)l;
            }
            #pragma unroll
            for (int t = 0; t < 2; ++t) {
                const int T = 2*wid + t;
                const size_t off = (size_t)(T*2 + c)*512 + lane*8;
                const bf16x8 Bhi = *(const bf16x8*)(w1hi + off);
                const bf16x8 Blo = *(const bf16x8*)(w1lo + off);
                acc[t] = __builtin_amdgcn_mfma_f32_16x16x32_bf16(Alo, Bhi, acc[t], 0, 0, 0);
                acc[t] = __builtin_amdgcn_mfma_f32_16x16x32_bf16(Ahi, Blo, acc[t], 0, 0, 0);
                acc[t] = __builtin_amdgcn_mfma_f32_16x16x32_bf16(Ahi, Bhi, acc[t], 0, 0, 0);
            }
        }
        #pragma unroll
        for (int t = 0; t < 2; ++t) {
            const int col = (2*wid + t)*16 + mrow;
            const float bb = b1[col];
            #pragma unroll
            for (int r = 0; r < 4; ++r)
                h1c[kg*4 + r][col] = pack_split(fmaxf(acc[t][r] + bb, 0.f));
        }
    }
    __syncthreads();

    // ================= layer 2: h2 = relu(h1 @ W2 + b2) ==================
    {
        f32x4 acc[2];
        acc[0] = (f32x4)0.f; acc[1] = (f32x4)0.f;
        #pragma unroll 2
        for (int c = 0; c < HDIM/32; ++c) {
            const uint4 u0 = *(const uint4*)&h1c[mrow][c*32 + kg*8];
            const uint4 u1 = *(const uint4*)&h1c[mrow][c*32 + kg*8 + 4];
            const unsigned uu[8] = {u0.x,u0.y,u0.z,u0.w,u1.x,u1.y,u1.z,u1.w};
            bf16x8 Ahi, Alo;
            #pragma unroll
            for (int j = 0; j < 8; ++j) {
                Ahi[j] = (short)(uu[j] & 0xFFFFu);
                Alo[j] = (short)(uu[j] >> 16);
            }
            #pragma unroll
            for (int t = 0; t < 2; ++t) {
                const int T = 2*wid + t;
                const size_t off = (size_t)(T*8 + c)*512 + lane*8;
                const bf16x8 Bhi = *(const bf16x8*)(w2hi + off);
                const bf16x8 Blo = *(const bf16x8*)(w2lo + off);
                acc[t] = __builtin_amdgcn_mfma_f32_16x16x32_bf16(Alo, Bhi, acc[t], 0, 0, 0);
                acc[t] = __builtin_amdgcn_mfma_f32_16x16x32_bf16(Ahi, Blo, acc[t], 0, 0, 0);
                acc[t] = __builtin_amdgcn_mfma_f32_16x16x32_bf16(Ahi, Bhi, acc[t], 0, 0, 0);
            }
        }
        #pragma unroll
        for (int t = 0; t < 2; ++t) {
            const int col = (2*wid + t)*16 + mrow;
            const float bb = b2[col];
            #pragma unroll
            for (int r = 0; r < 4; ++r)
                h2c[kg*4 + r][col] = pack_split(fmaxf(acc[t][r] + bb, 0.f));
        }
    }
    __syncthreads();

    // ================= layer 3: p = h2 @ W3 + b3 (waves 0-3) ===============
    if (wid < 4) {
        f32x4 acc = (f32x4)0.f;
        #pragma unroll 2
        for (int c = 0; c < HDIM/32; ++c) {
            const uint4 u0 = *(const uint4*)&h2c[mrow][c*32 + kg*8];
            const uint4 u1 = *(const uint4*)&h2c[mrow][c*32 + kg*8 + 4];
            const unsigned uu[8] = {u0.x,u0.y,u0.z,u0.w,u1.x,u1.y,u1.z,u1.w};
            bf16x8 Ahi, Alo;
            #pragma unroll
            for (int j = 0; j < 8; ++j) {
                Ahi[j] = (short)(uu[j] & 0xFFFFu);
                Alo[j] = (short)(uu[j] >> 16);
            }
            const size_t off = (size_t)(wid*8 + c)*512 + lane*8;
            const bf16x8 Bhi = *(const bf16x8*)(w3hi + off);
            const bf16x8 Blo = *(const bf16x8*)(w3lo + off);
            acc = __builtin_amdgcn_mfma_f32_16x16x32_bf16(Alo, Bhi, acc, 0, 0, 0);
            acc = __builtin_amdgcn_mfma_f32_16x16x32_bf16(Ahi, Blo, acc, 0, 0, 0);
            acc = __builtin_amdgcn_mfma_f32_16x16x32_bf16(Ahi, Bhi, acc, 0, 0, 0);
        }
        const int col = wid*16 + mrow;
        if (col < OUTP) {
            const float bb = b3[col];
            #pragma unroll
            for (int r = 0; r < 4; ++r)
                p_s[kg*4 + r][col] = acc[r] + bb;
        }
    }
    __syncthreads();

    // ---- softmax+cumsum / softplus -> prm_s
    if (tid < MROWS*3) {
        const int r   = tid / 3;
        const int seg = tid - 3*r;
        if (seg < 2) {
            const int   off   = (seg == 0) ? 0 : KB;
            const int   cbase = (seg == 0) ? 0 : 17;
            const float mb    = (seg == 0) ? MBW_ : MBH_;
            float m = -1e30f;
            #pragma unroll
            for (int i = 0; i < KB; ++i) m = fmaxf(m, p_s[r][off+i]);
            float e[KB];
            float s = 0.f;
            #pragma unroll
            for (int i = 0; i < KB; ++i) { e[i] = __expf(p_s[r][off+i] - m); s += e[i]; }
            const float span = (2.f*BOUNDF - (float)KB*mb) / s;
            float c = -BOUNDF;
            prm_s[r][cbase] = c;
            #pragma unroll
            for (int i = 0; i < KB; ++i) {
                c += mb + span*e[i];
                prm_s[r][cbase + 1 + i] = c;
            }
        } else {
            #pragma unroll
            for (int i = 0; i < KB+1; ++i) {
                const float x  = p_s[r][2*KB + i];
                const float sp = (x > 20.f) ? x : __logf(1.f + __expf(x));
                prm_s[r][34 + i] = MD_ + sp;
            }
        }
    }
    __syncthreads();

    for (int i = tid; i < MROWS*PSTR; i += 512)
        params[(size_t)row0*PSTR + i] = (&prm_s[0][0])[i];
}

// ---------------------------------------------------------------------------
// Spline application (verbatim R5 best): 4096 blocks (8 blocks/CU -> TLP for
// HBM streaming). Packed 32B bin records; single fast log.
// ---------------------------------------------------------------------------
__global__ __launch_bounds__(256) void spline_kernel(
    const float* __restrict__ y,
    const float* __restrict__ params,
    float* __restrict__ out,
    float* __restrict__ logdet)
{
    __shared__ float prm[PSTR];
    __shared__ float rec[KB][8];
    __shared__ float scan_s[KB];

    const int b   = blockIdx.x;
    const int tid = threadIdx.x;
    if (tid < PSTR) prm[tid] = params[(size_t)b*PSTR + tid];
    __syncthreads();
    if (tid < KB) {
        const int k = tid;
        rec[k][0] = prm[k];        rec[k][1] = prm[k+1];
        rec[k][2] = prm[17+k];     rec[k][3] = prm[17+k+1];
        rec[k][4] = prm[34+k];     rec[k][5] = prm[34+k+1];
        rec[k][6] = 0.f;           rec[k][7] = 0.f;
        scan_s[k] = prm[k+1];
    }
    __syncthreads();

    float cw[KB];
    #pragma unroll
    for (int q = 0; q < 4; ++q) {
        const float4 t4 = *(const float4*)&scan_s[4*q];
        cw[4*q+0] = t4.x; cw[4*q+1] = t4.y; cw[4*q+2] = t4.z; cw[4*q+3] = t4.w;
    }

    const size_t base = (size_t)b * NCOL + 4*tid;
    const float4 yv   = *(const float4*)(y + base);
    const float  yy[4] = {yv.x, yv.y, yv.z, yv.w};
    float ov[4], lv[4];

    #pragma unroll
    for (int i = 0; i < 4; ++i) {
        const float yi = yy[i];
        const bool outside = (yi < -BOUNDF) || (yi > BOUNDF);
        const float xc = fminf(fmaxf(yi, -BOUNDF), BOUNDF);
        int bin = 0;
        #pragma unroll
        for (int k = 0; k < KB; ++k) bin += (xc >= cw[k]) ? 1 : 0;
        bin = min(bin, KB-1);

        const float4 lo = *(const float4*)&rec[bin][0];
        const float2 hi = *(const float2*)&rec[bin][4];
        const float w  = lo.y - lo.x;
        const float hh = lo.w - lo.z;
        const float d0 = hi.x, d1 = hi.y;

        const float inv_w = __fdividef(1.f, w);
        const float delta = hh * inv_w;
        const float theta = (xc - lo.x) * inv_w;
        const float omt   = 1.f - theta;
        const float tt    = theta * theta;
        const float tomt  = theta * omt;
        const float num   = hh * (delta*tt + d0*tomt);
        const float den   = delta + (d0 + d1 - 2.f*delta)*tomt;
        const float o     = lo.z + __fdividef(num, den);
        const float der_num = fmaxf(delta*delta*(d1*tt + 2.f*delta*tomt + d0*omt*omt), 1e-12f);
        const float der_den = fmaxf(den*den, 1e-12f);
        const float ld      = __logf(__fdividef(der_num, der_den));

        ov[i] = outside ? yi : o;
        lv[i] = outside ? 0.f : ld;
    }

    *(float4*)(out + base)    = make_float4(ov[0], ov[1], ov[2], ov[3]);
    *(float4*)(logdet + base) = make_float4(lv[0], lv[1], lv[2], lv[3]);
}

extern "C" void kernel_launch(void* const* d_in, const int* in_sizes, int n_in,
                              void* d_out, int out_size, void* d_ws, size_t ws_size,
                              hipStream_t stream) {
    const float* cond = (const float*)d_in[0];
    const float* y    = (const float*)d_in[1];
    const float* W1   = (const float*)d_in[2];
    const float* b1   = (const float*)d_in[3];
    const float* W2   = (const float*)d_in[4];
    const float* b2   = (const float*)d_in[5];
    const float* W3   = (const float*)d_in[6];
    const float* b3   = (const float*)d_in[7];

    float* out    = (float*)d_out;
    float* logdet = out + (size_t)NROW * NCOL;

    // d_ws: params @0 (836 KB); tiled bf16 hi/lo weight planes @1MB.
    float* params = (float*)d_ws;
    unsigned short* w1hi = (unsigned short*)((char*)d_ws + (1 << 20));
    unsigned short* w1lo = w1hi + W1E;
    unsigned short* w2hi = w1lo + W1E;
    unsigned short* w2lo = w2hi + W2E;
    unsigned short* w3hi = w2lo + W2E;
    unsigned short* w3lo = w3hi + W3E;

    prep_weights<<<256, 256, 0, stream>>>(W1, W2, W3, w1hi, w1lo, w2hi, w2lo, w3hi, w3lo);
    mlp_mfma_kernel<<<NROW/MROWS, 512, 0, stream>>>(cond, b1, b2, b3,
                                                    w1hi, w1lo, w2hi, w2lo, w3hi, w3lo,
                                                    params);
    spline_kernel<<<NROW, 256, 0, stream>>>(y, params, out, logdet);
}

// Round 14
// 36.849 us; speedup vs baseline: 1.1508x; 1.0109x over previous
//
#include <hip/hip_runtime.h>
#include <math.h>

namespace {
constexpr int KB    = 16;        // spline bins
constexpr int OUTP  = 3*KB + 1;  // 49
constexpr int CDIM  = 64;
constexpr int HDIM  = 256;
constexpr int NCOL  = 1024;
constexpr int NROW  = 4096;
constexpr float BOUNDF = 5.0f;
constexpr float MBW_ = 0.001f;
constexpr float MBH_ = 0.001f;
constexpr float MD_  = 0.001f;
constexpr int PSTR  = 51;   // 17 cumw | 17 cumh | 17 deriv
constexpr int MROWS = 16;   // rows per MLP block
constexpr int HSTR  = 260;  // padded LDS stride (uints)
// tiled weight-plane sizes (elems): [tiles][chunks][kg:4][mrow:16][j:8]
constexpr int W1E = 16*2*512;   // 16384
constexpr int W2E = 16*8*512;   // 65536
constexpr int W3E = 4*8*512;    // 16384
}

typedef __attribute__((ext_vector_type(8))) short bf16x8;   // 8 bf16 (4 VGPR)
typedef __attribute__((ext_vector_type(4))) float f32x4;    // MFMA acc

__device__ __forceinline__ unsigned short f32_to_bf16_rne(float v) {
    unsigned u = __float_as_uint(v);
    return (unsigned short)((u + 0x7FFFu + ((u >> 16) & 1u)) >> 16);
}
__device__ __forceinline__ float bf16_to_f32(unsigned short h) {
    return __uint_as_float(((unsigned)h) << 16);
}
__device__ __forceinline__ void split_bf16(float v, unsigned short& hi, unsigned short& lo) {
    hi = f32_to_bf16_rne(v);
    lo = f32_to_bf16_rne(v - bf16_to_f32(hi));
}
__device__ __forceinline__ unsigned pack_split(float v) {
    unsigned short h, l; split_bf16(v, h, l);
    return (unsigned)h | ((unsigned)l << 16);
}

// tiled index for B-planes: from (k, col) -> [T][c][kg][mrow][j]
__device__ __forceinline__ int tiled_idx(int k, int col, int nchunk) {
    const int c = k >> 5, kg = (k >> 3) & 3, j = k & 7;
    const int T = col >> 4, mrow = col & 15;
    return ((T*nchunk + c) << 9) + (kg << 7) + (mrow << 3) + j;
}

// ---------------------------------------------------------------------------
// Prep (verbatim R13): coalesced reads, scattered 2B stores into tiled layout.
// ---------------------------------------------------------------------------
__global__ __launch_bounds__(256) void prep_weights(
    const float* __restrict__ W1, const float* __restrict__ W2,
    const float* __restrict__ W3,
    unsigned short* __restrict__ w1hi, unsigned short* __restrict__ w1lo,
    unsigned short* __restrict__ w2hi, unsigned short* __restrict__ w2lo,
    unsigned short* __restrict__ w3hi, unsigned short* __restrict__ w3lo)
{
    const int t = blockIdx.x * 256 + threadIdx.x;   // 0..65535
    {   // W2
        const int k = t >> 8, col = t & 255;
        unsigned short h, l; split_bf16(W2[t], h, l);
        const int d = tiled_idx(k, col, 8);
        w2hi[d] = h; w2lo[d] = l;
    }
    if (t < W1E) {   // W1: [64 k][256 col]
        const int k = t >> 8, col = t & 255;
        unsigned short h, l; split_bf16(W1[t], h, l);
        const int d = tiled_idx(k, col, 2);
        w1hi[d] = h; w1lo[d] = l;
    }
    if (t < W3E) {   // W3 padded [256 k][64 col]
        const int k = t >> 6, col = t & 63;
        const float v = (col < OUTP) ? W3[(size_t)k*OUTP + col] : 0.f;
        unsigned short h, l; split_bf16(v, h, l);
        const int d = tiled_idx(k, col, 8);
        w3hi[d] = h; w3lo[d] = l;
    }
}

// ---------------------------------------------------------------------------
// MFMA MLP, 8 waves, R13 structure + (a) 3-way independent accumulator
// chains (acc_hh/hl/lh -> 6 indep MFMA chains/wave) and (b) fully unrolled
// K-loops so all B loads can issue early. Fragment maps unchanged:
//   A: lane holds A[lane&15][(lane>>4)*8 + j]
//   B: lane kg*16+mrow holds B[c*32+kg*8+j][T*16+mrow]  (wave-tiled planes)
//   C: col = lane&15, row = (lane>>4)*4 + reg
// ---------------------------------------------------------------------------
__global__ __launch_bounds__(512) void mlp_mfma_kernel(
    const float* __restrict__ cond,
    const float* __restrict__ b1, const float* __restrict__ b2,
    const float* __restrict__ b3,
    const unsigned short* __restrict__ w1hi, const unsigned short* __restrict__ w1lo,
    const unsigned short* __restrict__ w2hi, const unsigned short* __restrict__ w2lo,
    const unsigned short* __restrict__ w3hi, const unsigned short* __restrict__ w3lo,
    float* __restrict__ params)
{
    __shared__ unsigned h1c[MROWS][HSTR];   // 16.6 KB packed h1 (hi|lo)
    __shared__ unsigned h2c[MROWS][HSTR];   // 16.6 KB packed h2
    __shared__ float    p_s[MROWS][OUTP];
    __shared__ float    prm_s[MROWS][PSTR];

    const int tid  = threadIdx.x;
    const int lane = tid & 63;
    const int wid  = tid >> 6;        // 0..7
    const int mrow = lane & 15;
    const int kg   = lane >> 4;
    const int row0 = blockIdx.x * MROWS;

    // ================= layer 1: h1 = relu(cond @ W1 + b1) ==================
    {
        f32x4 ahh[2], ahl[2], alh[2];
        #pragma unroll
        for (int t = 0; t < 2; ++t) { ahh[t] = (f32x4)0.f; ahl[t] = (f32x4)0.f; alh[t] = (f32x4)0.f; }

        #pragma unroll
        for (int c = 0; c < CDIM/32; ++c) {
            const float* ap = cond + (size_t)(row0 + mrow)*CDIM + c*32 + kg*8;
            const float4 a0 = *(const float4*)ap;
            const float4 a1 = *(const float4*)(ap + 4);
            const float av[8] = {a0.x,a0.y,a0.z,a0.w,a1.x,a1.y,a1.z,a1.w};
            bf16x8 Ahi, Alo;
            #pragma unroll
            for (int j = 0; j < 8; ++j) {
                unsigned short h, l; split_bf16(av[j], h, l);
                Ahi[j] = (short)h; Alo[j] = (short)l;
            }
            #pragma unroll
            for (int t = 0; t < 2; ++t) {
                const int T = 2*wid + t;
                const size_t off = (size_t)(T*2 + c)*512 + lane*8;
                const bf16x8 Bhi = *(const bf16x8*)(w1hi + off);
                const bf16x8 Blo = *(const bf16x8*)(w1lo + off);
                ahh[t] = __builtin_amdgcn_mfma_f32_16x16x32_bf16(Ahi, Bhi, ahh[t], 0, 0, 0);
                ahl[t] = __builtin_amdgcn_mfma_f32_16x16x32_bf16(Ahi, Blo, ahl[t], 0, 0, 0);
                alh[t] = __builtin_amdgcn_mfma_f32_16x16x32_bf16(Alo, Bhi, alh[t], 0, 0, 0);
            }
        }
        #pragma unroll
        for (int t = 0; t < 2; ++t) {
            const int col = (2*wid + t)*16 + mrow;
            const float bb = b1[col];
            #pragma unroll
            for (int r = 0; r < 4; ++r) {
                const float v = fmaxf(ahh[t][r] + ahl[t][r] + alh[t][r] + bb, 0.f);
                h1c[kg*4 + r][col] = pack_split(v);
            }
        }
    }
    __syncthreads();

    // ================= layer 2: h2 = relu(h1 @ W2 + b2) ==================
    {
        f32x4 ahh[2], ahl[2], alh[2];
        #pragma unroll
        for (int t = 0; t < 2; ++t) { ahh[t] = (f32x4)0.f; ahl[t] = (f32x4)0.f; alh[t] = (f32x4)0.f; }

        #pragma unroll
        for (int c = 0; c < HDIM/32; ++c) {               // fully unrolled (8)
            const uint4 u0 = *(const uint4*)&h1c[mrow][c*32 + kg*8];
            const uint4 u1 = *(const uint4*)&h1c[mrow][c*32 + kg*8 + 4];
            const unsigned uu[8] = {u0.x,u0.y,u0.z,u0.w,u1.x,u1.y,u1.z,u1.w};
            bf16x8 Ahi, Alo;
            #pragma unroll
            for (int j = 0; j < 8; ++j) {
                Ahi[j] = (short)(uu[j] & 0xFFFFu);
                Alo[j] = (short)(uu[j] >> 16);
            }
            #pragma unroll
            for (int t = 0; t < 2; ++t) {
                const int T = 2*wid + t;
                const size_t off = (size_t)(T*8 + c)*512 + lane*8;
                const bf16x8 Bhi = *(const bf16x8*)(w2hi + off);
                const bf16x8 Blo = *(const bf16x8*)(w2lo + off);
                ahh[t] = __builtin_amdgcn_mfma_f32_16x16x32_bf16(Ahi, Bhi, ahh[t], 0, 0, 0);
                ahl[t] = __builtin_amdgcn_mfma_f32_16x16x32_bf16(Ahi, Blo, ahl[t], 0, 0, 0);
                alh[t] = __builtin_amdgcn_mfma_f32_16x16x32_bf16(Alo, Bhi, alh[t], 0, 0, 0);
            }
        }
        #pragma unroll
        for (int t = 0; t < 2; ++t) {
            const int col = (2*wid + t)*16 + mrow;
            const float bb = b2[col];
            #pragma unroll
            for (int r = 0; r < 4; ++r) {
                const float v = fmaxf(ahh[t][r] + ahl[t][r] + alh[t][r] + bb, 0.f);
                h2c[kg*4 + r][col] = pack_split(v);
            }
        }
    }
    __syncthreads();

    // ================= layer 3: p = h2 @ W3 + b3 (waves 0-3) ===============
    if (wid < 4) {
        f32x4 ahh = (f32x4)0.f, ahl = (f32x4)0.f, alh = (f32x4)0.f;
        #pragma unroll
        for (int c = 0; c < HDIM/32; ++c) {               // fully unrolled (8)
            const uint4 u0 = *(const uint4*)&h2c[mrow][c*32 + kg*8];
            const uint4 u1 = *(const uint4*)&h2c[mrow][c*32 + kg*8 + 4];
            const unsigned uu[8] = {u0.x,u0.y,u0.z,u0.w,u1.x,u1.y,u1.z,u1.w};
            bf16x8 Ahi, Alo;
            #pragma unroll
            for (int j = 0; j < 8; ++j) {
                Ahi[j] = (short)(uu[j] & 0xFFFFu);
                Alo[j] = (short)(uu[j] >> 16);
            }
            const size_t off = (size_t)(wid*8 + c)*512 + lane*8;
            const bf16x8 Bhi = *(const bf16x8*)(w3hi + off);
            const bf16x8 Blo = *(const bf16x8*)(w3lo + off);
            ahh = __builtin_amdgcn_mfma_f32_16x16x32_bf16(Ahi, Bhi, ahh, 0, 0, 0);
            ahl = __builtin_amdgcn_mfma_f32_16x16x32_bf16(Ahi, Blo, ahl, 0, 0, 0);
            alh = __builtin_amdgcn_mfma_f32_16x16x32_bf16(Alo, Bhi, alh, 0, 0, 0);
        }
        const int col = wid*16 + mrow;
        if (col < OUTP) {
            const float bb = b3[col];
            #pragma unroll
            for (int r = 0; r < 4; ++r)
                p_s[kg*4 + r][col] = ahh[r] + ahl[r] + alh[r] + bb;
        }
    }
    __syncthreads();

    // ---- softmax+cumsum / softplus -> prm_s
    if (tid < MROWS*3) {
        const int r   = tid / 3;
        const int seg = tid - 3*r;
        if (seg < 2) {
            const int   off   = (seg == 0) ? 0 : KB;
            const int   cbase = (seg == 0) ? 0 : 17;
            const float mb    = (seg == 0) ? MBW_ : MBH_;
            float m = -1e30f;
            #pragma unroll
            for (int i = 0; i < KB; ++i) m = fmaxf(m, p_s[r][off+i]);
            float e[KB];
            float s = 0.f;
            #pragma unroll
            for (int i = 0; i < KB; ++i) { e[i] = __expf(p_s[r][off+i] - m); s += e[i]; }
            const float span = (2.f*BOUNDF - (float)KB*mb) / s;
            float c = -BOUNDF;
            prm_s[r][cbase] = c;
            #pragma unroll
            for (int i = 0; i < KB; ++i) {
                c += mb + span*e[i];
                prm_s[r][cbase + 1 + i] = c;
            }
        } else {
            #pragma unroll
            for (int i = 0; i < KB+1; ++i) {
                const float x  = p_s[r][2*KB + i];
                const float sp = (x > 20.f) ? x : __logf(1.f + __expf(x));
                prm_s[r][34 + i] = MD_ + sp;
            }
        }
    }
    __syncthreads();

    for (int i = tid; i < MROWS*PSTR; i += 512)
        params[(size_t)row0*PSTR + i] = (&prm_s[0][0])[i];
}

// ---------------------------------------------------------------------------
// Spline application (verbatim R5/R13 best): 4096 blocks, packed 32B bin
// records, single fast log.
// ---------------------------------------------------------------------------
__global__ __launch_bounds__(256) void spline_kernel(
    const float* __restrict__ y,
    const float* __restrict__ params,
    float* __restrict__ out,
    float* __restrict__ logdet)
{
    __shared__ float prm[PSTR];
    __shared__ float rec[KB][8];
    __shared__ float scan_s[KB];

    const int b   = blockIdx.x;
    const int tid = threadIdx.x;
    if (tid < PSTR) prm[tid] = params[(size_t)b*PSTR + tid];
    __syncthreads();
    if (tid < KB) {
        const int k = tid;
        rec[k][0] = prm[k];        rec[k][1] = prm[k+1];
        rec[k][2] = prm[17+k];     rec[k][3] = prm[17+k+1];
        rec[k][4] = prm[34+k];     rec[k][5] = prm[34+k+1];
        rec[k][6] = 0.f;           rec[k][7] = 0.f;
        scan_s[k] = prm[k+1];
    }
    __syncthreads();

    float cw[KB];
    #pragma unroll
    for (int q = 0; q < 4; ++q) {
        const float4 t4 = *(const float4*)&scan_s[4*q];
        cw[4*q+0] = t4.x; cw[4*q+1] = t4.y; cw[4*q+2] = t4.z; cw[4*q+3] = t4.w;
    }

    const size_t base = (size_t)b * NCOL + 4*tid;
    const float4 yv   = *(const float4*)(y + base);
    const float  yy[4] = {yv.x, yv.y, yv.z, yv.w};
    float ov[4], lv[4];

    #pragma unroll
    for (int i = 0; i < 4; ++i) {
        const float yi = yy[i];
        const bool outside = (yi < -BOUNDF) || (yi > BOUNDF);
        const float xc = fminf(fmaxf(yi, -BOUNDF), BOUNDF);
        int bin = 0;
        #pragma unroll
        for (int k = 0; k < KB; ++k) bin += (xc >= cw[k]) ? 1 : 0;
        bin = min(bin, KB-1);

        const float4 lo = *(const float4*)&rec[bin][0];
        const float2 hi = *(const float2*)&rec[bin][4];
        const float w  = lo.y - lo.x;
        const float hh = lo.w - lo.z;
        const float d0 = hi.x, d1 = hi.y;

        const float inv_w = __fdividef(1.f, w);
        const float delta = hh * inv_w;
        const float theta = (xc - lo.x) * inv_w;
        const float omt   = 1.f - theta;
        const float tt    = theta * theta;
        const float tomt  = theta * omt;
        const float num   = hh * (delta*tt + d0*tomt);
        const float den   = delta + (d0 + d1 - 2.f*delta)*tomt;
        const float o     = lo.z + __fdividef(num, den);
        const float der_num = fmaxf(delta*delta*(d1*tt + 2.f*delta*tomt + d0*omt*omt), 1e-12f);
        const float der_den = fmaxf(den*den, 1e-12f);
        const float ld      = __logf(__fdividef(der_num, der_den));

        ov[i] = outside ? yi : o;
        lv[i] = outside ? 0.f : ld;
    }

    *(float4*)(out + base)    = make_float4(ov[0], ov[1], ov[2], ov[3]);
    *(float4*)(logdet + base) = make_float4(lv[0], lv[1], lv[2], lv[3]);
}

extern "C" void kernel_launch(void* const* d_in, const int* in_sizes, int n_in,
                              void* d_out, int out_size, void* d_ws, size_t ws_size,
                              hipStream_t stream) {
    const float* cond = (const float*)d_in[0];
    const float* y    = (const float*)d_in[1];
    const float* W1   = (const float*)d_in[2];
    const float* b1   = (const float*)d_in[3];
    const float* W2   = (const float*)d_in[4];
    const float* b2   = (const float*)d_in[5];
    const float* W3   = (const float*)d_in[6];
    const float* b3   = (const float*)d_in[7];

    float* out    = (float*)d_out;
    float* logdet = out + (size_t)NROW * NCOL;

    // d_ws: params @0 (836 KB); tiled bf16 hi/lo weight planes @1MB.
    float* params = (float*)d_ws;
    unsigned short* w1hi = (unsigned short*)((char*)d_ws + (1 << 20));
    unsigned short* w1lo = w1hi + W1E;
    unsigned short* w2hi = w1lo + W1E;
    unsigned short* w2lo = w2hi + W2E;
    unsigned short* w3hi = w2lo + W2E;
    unsigned short* w3lo = w3hi + W3E;

    prep_weights<<<256, 256, 0, stream>>>(W1, W2, W3, w1hi, w1lo, w2hi, w2lo, w3hi, w3lo);
    mlp_mfma_kernel<<<NROW/MROWS, 512, 0, stream>>>(cond, b1, b2, b3,
                                                    w1hi, w1lo, w2hi, w2lo, w3hi, w3lo,
                                                    params);
    spline_kernel<<<NROW, 256, 0, stream>>>(y, params, out, logdet);
}